// Round 5
// baseline (451.142 us; speedup 1.0000x reference)
//
#include <hip/hip_runtime.h>
#include <hip/hip_bf16.h>

typedef __attribute__((ext_vector_type(4))) float f32x4;
typedef __attribute__((ext_vector_type(8))) short bf16x8;

#define GAS __attribute__((address_space(1)))
#define LAS __attribute__((address_space(3)))

__device__ __forceinline__ unsigned int cvtpk(float lo, float hi) {
  unsigned int r;
  asm("v_cvt_pk_bf16_f32 %0, %1, %2" : "=v"(r) : "v"(lo), "v"(hi));
  return r;
}
__device__ __forceinline__ unsigned short f2bf(float f) { return (unsigned short)cvtpk(f, f); }
__device__ __forceinline__ f32x4 mfma16(bf16x8 a, bf16x8 b, f32x4 c) {
  return __builtin_amdgcn_mfma_f32_16x16x32_bf16(a, b, c, 0, 0, 0);
}
__device__ __forceinline__ void gl_lds16(const unsigned short* g, unsigned short* l) {
  __builtin_amdgcn_global_load_lds((const GAS unsigned short*)g, (LAS unsigned short*)l, 16, 0, 0);
}
__device__ __forceinline__ void memfence_sched() { asm volatile("" ::: "memory"); }

__global__ __launch_bounds__(256)
void cvt_f32_bf16(const float* __restrict__ in, unsigned short* __restrict__ out, int n8) {
  for (int i = blockIdx.x * blockDim.x + threadIdx.x; i < n8; i += gridDim.x * blockDim.x) {
    const float4 a = *reinterpret_cast<const float4*>(in + (size_t)i * 8);
    const float4 b = *reinterpret_cast<const float4*>(in + (size_t)i * 8 + 4);
    uint4 o;
    o.x = cvtpk(a.x, a.y); o.y = cvtpk(a.z, a.w);
    o.z = cvtpk(b.x, b.y); o.w = cvtpk(b.z, b.w);
    *reinterpret_cast<uint4*>(out + (size_t)i * 8) = o;
  }
}

// C[M,N] = A[M,512] @ B[N,512]^T. fp32 operand (F): reg-staged depth-3
// (3 reg banks) + cvt_pk + swizzled ds_write (2 LDS slots). bf16 operand (G):
// global_load_lds depth-2 (3 LDS slots, pre-swizzled source, L2-hot weights).
// BK=32, 16 K-steps. Steady waits: mid vmcnt(12) -> write F(kt+1);
// end vmcnt(10) -> G(kt+1) ready. Counted tail, never-0 until drain.
// 256x256 tile, 512 thr (8 waves 2x4), per-wave 128x64.
// MODE 0: bf16 *0.125 ; MODE 1: bf16 ; MODE 2: f32 + bias.
template<int MODE, bool AF32, bool BF32>
__global__ __launch_bounds__(512, 2)
void gemm8(const void* __restrict__ Agv, const void* __restrict__ Bgv,
           void* __restrict__ Cg, const float* __restrict__ bias, int ntn, size_t ldc)
{
  constexpr bool MIXED = AF32 || BF32;
  constexpr int NA = AF32 ? 2 : 3;
  constexpr int NB = BF32 ? 2 : 3;
  __shared__ unsigned short sm[(NA + NB) * 8192];
  unsigned short* const smB = sm + NA * 8192;

  const int t = threadIdx.x, lane = t & 63, w = t >> 6;
  const int lo = lane & 15, hi = lane >> 4;
  const int wm = w >> 2, wn = w & 3;
  const int nwg = gridDim.x, bid = blockIdx.x;
  const int id = (bid & 7) * (nwg >> 3) + (bid >> 3);   // XCD swizzle (nwg%8==0)
  const int row0 = (id / ntn) * 256, col0 = (id % ntn) * 256;
  const int w16 = w * 16;

  const unsigned short* Ab = (const unsigned short*)Agv;
  const unsigned short* Bb = (const unsigned short*)Bgv;
  const float* Ff = AF32 ? (const float*)Agv : (const float*)Bgv;
  const int frow0 = AF32 ? row0 : col0;

  // gl_lds path addressing (pre-swizzled source)
  const int cxor_g = (lane >> 3) & 3;
  const size_t a_src_g = (size_t)(row0 + w16 + (lane >> 2)) * 512 + (((lane & 3) ^ cxor_g) << 3);
  const size_t b_src_g = (size_t)(col0 + w16 + (lane >> 2)) * 512 + (((lane & 3) ^ cxor_g) << 3);

  // f32 reg-staged addressing
  const int rs_r = t >> 2;                 // row within 128-row half
  const int rs_c = (t & 3) * 8;            // col within 32
  const int wch = ((t & 3) ^ ((t >> 3) & 3)) << 3;   // swizzled ush offset in row

  float4 stF[3][4];                        // [bank][piece], bank = stage % 3

  auto F_ISSUE = [&](int kt) {
    if constexpr (MIXED) {
      const int bk = kt % 3;
      const float* s0 = Ff + (size_t)(frow0 + rs_r) * 512 + kt * 32 + rs_c;
      const float* s1 = Ff + (size_t)(frow0 + 128 + rs_r) * 512 + kt * 32 + rs_c;
      stF[bk][0] = *(const float4*)s0; stF[bk][1] = *(const float4*)(s0 + 4);
      stF[bk][2] = *(const float4*)s1; stF[bk][3] = *(const float4*)(s1 + 4);
    }
  };
  auto F_WRITE = [&](int kt) {
    if constexpr (MIXED) {
      const int bk = kt % 3;
      unsigned short* fb = AF32 ? &sm[(kt % NA) * 8192] : &smB[(kt % NB) * 8192];
      uint4 o;
      o.x = cvtpk(stF[bk][0].x, stF[bk][0].y); o.y = cvtpk(stF[bk][0].z, stF[bk][0].w);
      o.z = cvtpk(stF[bk][1].x, stF[bk][1].y); o.w = cvtpk(stF[bk][1].z, stF[bk][1].w);
      *reinterpret_cast<uint4*>(&fb[rs_r * 32 + wch]) = o;
      o.x = cvtpk(stF[bk][2].x, stF[bk][2].y); o.y = cvtpk(stF[bk][2].z, stF[bk][2].w);
      o.z = cvtpk(stF[bk][3].x, stF[bk][3].y); o.w = cvtpk(stF[bk][3].z, stF[bk][3].w);
      *reinterpret_cast<uint4*>(&fb[(128 + rs_r) * 32 + wch]) = o;
    }
  };
  auto G_ISSUE = [&](int kt) {
    if constexpr (!AF32) {                 // A via gl_lds
      unsigned short* ab = &sm[(kt % NA) * 8192];
      gl_lds16(Ab + a_src_g + kt * 32, ab + w16 * 32);
      gl_lds16(Ab + a_src_g + (size_t)128 * 512 + kt * 32, ab + (128 + w16) * 32);
    }
    if constexpr (!BF32) {                 // B via gl_lds
      unsigned short* bb = &smB[(kt % NB) * 8192];
      gl_lds16(Bb + b_src_g + kt * 32, bb + w16 * 32);
      gl_lds16(Bb + b_src_g + (size_t)128 * 512 + kt * 32, bb + (128 + w16) * 32);
    }
  };

  f32x4 acc[8][4] = {};
  const int fxor = (hi ^ ((lo >> 1) & 3)) << 3;

  // ---- prologue ----
  if constexpr (MIXED) {
    F_ISSUE(0);
    G_ISSUE(0); F_ISSUE(1);
    G_ISSUE(1); F_ISSUE(2);
    memfence_sched();
    asm volatile("s_waitcnt vmcnt(12)" ::: "memory");   // F(0) done
    F_WRITE(0);
    asm volatile("s_waitcnt vmcnt(10)" ::: "memory");   // G(0) done
  } else {
    G_ISSUE(0); G_ISSUE(1);
    memfence_sched();
    asm volatile("s_waitcnt vmcnt(4)" ::: "memory");    // stage 0 done
  }
  asm volatile("s_waitcnt lgkmcnt(0)" ::: "memory");
  __builtin_amdgcn_s_barrier();
  memfence_sched();

  // ---- main loop ----
  #pragma unroll
  for (int kt = 0; kt < 16; ++kt) {
    const unsigned short* ab = &sm[(kt % NA) * 8192];
    const unsigned short* bb = &smB[(kt % NB) * 8192];
    bf16x8 bfr[4], af[4];
    #pragma unroll
    for (int nj = 0; nj < 4; ++nj)
      bfr[nj] = *reinterpret_cast<const bf16x8*>(&bb[(wn * 64 + nj * 16 + lo) * 32 + fxor]);
    #pragma unroll
    for (int mi = 0; mi < 4; ++mi)
      af[mi] = *reinterpret_cast<const bf16x8*>(&ab[(wm * 128 + mi * 16 + lo) * 32 + fxor]);

    if constexpr (MIXED) {
      if (kt <= 13) G_ISSUE(kt + 2);
      if (kt <= 12) F_ISSUE(kt + 3);
    } else {
      if (kt <= 13) G_ISSUE(kt + 2);
    }
    memfence_sched();

    __builtin_amdgcn_s_setprio(1);
    #pragma unroll
    for (int mi = 0; mi < 4; ++mi)
      #pragma unroll
      for (int nj = 0; nj < 4; ++nj)
        acc[mi][nj] = mfma16(af[mi], bfr[nj], acc[mi][nj]);
    __builtin_amdgcn_s_setprio(0);

    #pragma unroll
    for (int mi = 0; mi < 4; ++mi)
      af[mi] = *reinterpret_cast<const bf16x8*>(&ab[(wm * 128 + (mi + 4) * 16 + lo) * 32 + fxor]);

    if constexpr (MIXED) {
      if (kt <= 12)      { asm volatile("s_waitcnt vmcnt(12)" ::: "memory"); }
      else if (kt == 13) { asm volatile("s_waitcnt vmcnt(8)"  ::: "memory"); }
      else if (kt == 14) { asm volatile("s_waitcnt vmcnt(2)"  ::: "memory"); }
      if (kt <= 14) F_WRITE(kt + 1);
    }

    __builtin_amdgcn_s_setprio(1);
    #pragma unroll
    for (int mi = 0; mi < 4; ++mi)
      #pragma unroll
      for (int nj = 0; nj < 4; ++nj)
        acc[mi + 4][nj] = mfma16(af[mi], bfr[nj], acc[mi + 4][nj]);
    __builtin_amdgcn_s_setprio(0);

    if (kt < 15) {
      if constexpr (MIXED) {
        if (kt <= 12)      { asm volatile("s_waitcnt vmcnt(10)" ::: "memory"); }
        else if (kt == 13) { asm volatile("s_waitcnt vmcnt(6)"  ::: "memory"); }
        else               { asm volatile("s_waitcnt vmcnt(0)"  ::: "memory"); }
      } else {
        if (kt <= 13)      { asm volatile("s_waitcnt vmcnt(4)" ::: "memory"); }
        else               { asm volatile("s_waitcnt vmcnt(0)" ::: "memory"); }
      }
      asm volatile("s_waitcnt lgkmcnt(0)" ::: "memory");
      __builtin_amdgcn_s_barrier();
      memfence_sched();
    }
  }

  #pragma unroll
  for (int mi = 0; mi < 8; ++mi) {
    #pragma unroll
    for (int r = 0; r < 4; ++r) {
      const size_t gm = (size_t)row0 + wm * 128 + mi * 16 + hi * 4 + r;
      #pragma unroll
      for (int nj = 0; nj < 4; ++nj) {
        const int gn = col0 + wn * 64 + nj * 16 + lo;
        const float v = acc[mi][nj][r];
        if constexpr (MODE == 0)
          ((unsigned short*)Cg)[gm * ldc + gn] = f2bf(v * 0.125f);
        else if constexpr (MODE == 1)
          ((unsigned short*)Cg)[gm * ldc + gn] = f2bf(v);
        else
          ((float*)Cg)[gm * ldc + gn] = v + bias[gn];
      }
    }
  }
}

// Flash attention, KV split 4-way: grid = 2048 (b,h,qhalf,chunk), 256 thr
// (4 waves x 16 q-rows). Writes partials (o fp32, m, l) for combine pass.
// k [131072, 512] bf16 (col h*64+d); vT [512, 131072] bf16.
__global__ __launch_bounds__(256)
void attn_fwd(const unsigned short* __restrict__ qh,
              const unsigned short* __restrict__ kbuf,
              const unsigned short* __restrict__ vT,
              const float* __restrict__ mask,
              float* __restrict__ opart, float* __restrict__ ml)
{
  __shared__ unsigned short Ks[64 * 64];
  __shared__ unsigned short Vs[64 * 64];
  __shared__ unsigned short Ps[4][16 * 64];
  const int bid = blockIdx.x;
  const int xcd = bid & 7, g = bid >> 3;
  const int b = (g >> 6) * 8 + xcd;           // blocks sharing b land on one XCD
  const int sub = g & 63;
  const int h = sub >> 3, qhalf = (sub >> 2) & 1, c = sub & 3;
  const int n0 = c * 1024;
  const int bh2 = (b * 8 + h) * 2 + qhalf;
  const int t = threadIdx.x, lane = t & 63, w = t >> 6;
  const int hi = lane >> 4, lo = lane & 15;
  const int q0 = qhalf * 64 + w * 16;

  bf16x8 aq[2];
  #pragma unroll
  for (int kk = 0; kk < 2; ++kk)
    aq[kk] = *reinterpret_cast<const bf16x8*>(
        qh + (size_t)(b * 128 + q0 + lo) * 512 + h * 64 + kk * 32 + hi * 8);

  float mrow[4], lrow[4];
  #pragma unroll
  for (int i = 0; i < 4; ++i) { mrow[i] = -1e30f; lrow[i] = 0.f; }
  f32x4 o[4] = {};

  const unsigned short* kp = kbuf + ((size_t)b * 4096 + n0) * 512 + h * 64;
  const unsigned short* vp = vT + (size_t)(h * 64) * 131072 + (size_t)b * 4096 + n0;
  const float* mp = mask + ((size_t)(b * 128 + q0)) * 4096 + n0;

  for (int nt = 0; nt < 16; ++nt) {
    {
      const int r = t >> 3, cc = t & 7;
      *reinterpret_cast<uint4*>(&Ks[r * 64 + ((cc ^ (r & 7)) << 3)]) =
          *reinterpret_cast<const uint4*>(kp + (size_t)(nt * 64 + r) * 512 + (cc << 3));
      *reinterpret_cast<uint4*>(&Ks[(r + 32) * 64 + ((cc ^ (r & 7)) << 3)]) =
          *reinterpret_cast<const uint4*>(kp + (size_t)(nt * 64 + r + 32) * 512 + (cc << 3));
      *reinterpret_cast<uint4*>(&Vs[r * 64 + ((cc ^ (r & 7)) << 3)]) =
          *reinterpret_cast<const uint4*>(vp + (size_t)r * 131072 + nt * 64 + (cc << 3));
      *reinterpret_cast<uint4*>(&Vs[(r + 32) * 64 + ((cc ^ (r & 7)) << 3)]) =
          *reinterpret_cast<const uint4*>(vp + (size_t)(r + 32) * 131072 + nt * 64 + (cc << 3));
    }
    __syncthreads();

    f32x4 s[4] = {};
    __builtin_amdgcn_s_setprio(1);
    #pragma unroll
    for (int ni = 0; ni < 4; ++ni) {
      #pragma unroll
      for (int kk = 0; kk < 2; ++kk) {
        const bf16x8 kf = *reinterpret_cast<const bf16x8*>(
            &Ks[(ni * 16 + lo) * 64 + ((kk * 32 + hi * 8) ^ ((lo & 7) << 3))]);
        s[ni] = mfma16(aq[kk], kf, s[ni]);
      }
    }
    __builtin_amdgcn_s_setprio(0);
    #pragma unroll
    for (int ni = 0; ni < 4; ++ni)
      #pragma unroll
      for (int r = 0; r < 4; ++r)
        s[ni][r] += mp[(size_t)(hi * 4 + r) * 4096 + nt * 64 + ni * 16 + lo];

    #pragma unroll
    for (int r = 0; r < 4; ++r) {
      float mx = fmaxf(fmaxf(s[0][r], s[1][r]), fmaxf(s[2][r], s[3][r]));
      #pragma unroll
      for (int off = 1; off < 16; off <<= 1)
        mx = fmaxf(mx, __shfl_xor(mx, off, 64));
      const float mnew = fmaxf(mrow[r], mx);
      const float corr = __expf(mrow[r] - mnew);
      mrow[r] = mnew;
      float ls = 0.f;
      #pragma unroll
      for (int ni = 0; ni < 4; ++ni) {
        const float p = __expf(s[ni][r] - mnew);
        s[ni][r] = p; ls += p;
      }
      #pragma unroll
      for (int off = 1; off < 16; off <<= 1)
        ls += __shfl_xor(ls, off, 64);
      lrow[r] = lrow[r] * corr + ls;
      #pragma unroll
      for (int di = 0; di < 4; ++di)
        o[di][r] *= corr;
    }

    #pragma unroll
    for (int ni = 0; ni < 4; ++ni)
      #pragma unroll
      for (int r = 0; r < 4; ++r) {
        const int rp = hi * 4 + r;
        Ps[w][rp * 64 + ((ni * 16 + lo) ^ ((rp & 7) << 3))] = f2bf(s[ni][r]);
      }

    __builtin_amdgcn_s_setprio(1);
    #pragma unroll
    for (int kk = 0; kk < 2; ++kk) {
      const bf16x8 pa = *reinterpret_cast<const bf16x8*>(
          &Ps[w][lo * 64 + ((kk * 32 + hi * 8) ^ ((lo & 7) << 3))]);
      #pragma unroll
      for (int di = 0; di < 4; ++di) {
        const bf16x8 vf = *reinterpret_cast<const bf16x8*>(
            &Vs[(di * 16 + lo) * 64 + ((kk * 32 + hi * 8) ^ ((lo & 7) << 3))]);
        o[di] = mfma16(pa, vf, o[di]);
      }
    }
    __builtin_amdgcn_s_setprio(0);
    __syncthreads();
  }

  // store partials (no division)
  const size_t pbase = ((size_t)bh2 * 4 + c) * 64;
  #pragma unroll
  for (int di = 0; di < 4; ++di)
    #pragma unroll
    for (int r = 0; r < 4; ++r)
      opart[(pbase + (w * 16 + hi * 4 + r)) * 64 + di * 16 + lo] = o[di][r];
  if (lo == 0) {
    #pragma unroll
    for (int r = 0; r < 4; ++r) {
      const int qq = w * 16 + hi * 4 + r;
      ml[(((size_t)bh2 * 4 + c) * 2 + 0) * 64 + qq] = mrow[r];
      ml[(((size_t)bh2 * 4 + c) * 2 + 1) * 64 + qq] = lrow[r];
    }
  }
}

// Combine 4 chunk-partials -> xb bf16. grid = 512 (bh2), 256 thr.
__global__ __launch_bounds__(256)
void attn_combine(const float* __restrict__ opart, const float* __restrict__ ml,
                  unsigned short* __restrict__ xb)
{
  const int bh2 = blockIdx.x;
  const int b = bh2 >> 4, h = (bh2 >> 1) & 7, qhalf = bh2 & 1;
  const int t = threadIdx.x;
  const int q = t >> 2, dg = t & 3;

  float m[4], l[4];
  #pragma unroll
  for (int c = 0; c < 4; ++c) {
    m[c] = ml[(((size_t)bh2 * 4 + c) * 2 + 0) * 64 + q];
    l[c] = ml[(((size_t)bh2 * 4 + c) * 2 + 1) * 64 + q];
  }
  const float M = fmaxf(fmaxf(m[0], m[1]), fmaxf(m[2], m[3]));
  float sc[4], L = 0.f;
  #pragma unroll
  for (int c = 0; c < 4; ++c) { sc[c] = __expf(m[c] - M); L += sc[c] * l[c]; }
  const float inv = 1.f / L;

  float4 acc[4] = {};
  #pragma unroll
  for (int c = 0; c < 4; ++c) {
    const float* base = opart + (((size_t)bh2 * 4 + c) * 64 + q) * 64 + dg * 16;
    #pragma unroll
    for (int j = 0; j < 4; ++j) {
      const float4 v = *reinterpret_cast<const float4*>(base + j * 4);
      acc[j].x = fmaf(sc[c], v.x, acc[j].x);
      acc[j].y = fmaf(sc[c], v.y, acc[j].y);
      acc[j].z = fmaf(sc[c], v.z, acc[j].z);
      acc[j].w = fmaf(sc[c], v.w, acc[j].w);
    }
  }
  unsigned short* dst = xb + ((size_t)b * 128 + qhalf * 64 + q) * 512 + h * 64 + dg * 16;
  uint4 o1, o2;
  o1.x = cvtpk(acc[0].x * inv, acc[0].y * inv); o1.y = cvtpk(acc[0].z * inv, acc[0].w * inv);
  o1.z = cvtpk(acc[1].x * inv, acc[1].y * inv); o1.w = cvtpk(acc[1].z * inv, acc[1].w * inv);
  o2.x = cvtpk(acc[2].x * inv, acc[2].y * inv); o2.y = cvtpk(acc[2].z * inv, acc[2].w * inv);
  o2.z = cvtpk(acc[3].x * inv, acc[3].y * inv); o2.w = cvtpk(acc[3].z * inv, acc[3].w * inv);
  *reinterpret_cast<uint4*>(dst) = o1;
  *reinterpret_cast<uint4*>(dst + 8) = o2;
}

extern "C" void kernel_launch(void* const* d_in, const int* in_sizes, int n_in,
                              void* d_out, int out_size, void* d_ws, size_t ws_size,
                              hipStream_t stream) {
  const float* q     = (const float*)d_in[0];
  const float* kv    = (const float*)d_in[1];
  const float* mask  = (const float*)d_in[2];
  const float* Wq    = (const float*)d_in[3];
  const float* Wkv   = (const float*)d_in[4];
  const float* Wproj = (const float*)d_in[5];
  const float* bproj = (const float*)d_in[6];
  float* out = (float*)d_out;

  char* ws = (char*)d_ws;
  unsigned short* kbuf   = (unsigned short*)ws;                      // 134.2 MB [131072,512]
  unsigned short* vTb    = (unsigned short*)(ws + 134217728ULL);     // 134.2 MB [512,131072]
  float*          opart  = (float*)(ws + 268435456ULL);              // 33.6 MB [512][4][64][64]
  float*          mlb    = (float*)(ws + 301989888ULL);              // 1.0 MB  [512][4][2][64]
  unsigned short* qhb    = (unsigned short*)(ws + 303038464ULL);     // 4.2 MB
  unsigned short* xb     = (unsigned short*)(ws + 307232768ULL);     // 4.2 MB
  unsigned short* Wqb    = (unsigned short*)(ws + 311427072ULL);     // 0.5 MB
  unsigned short* Wkvb   = (unsigned short*)(ws + 311951360ULL);     // 1.0 MB
  unsigned short* Wprojb = (unsigned short*)(ws + 312999936ULL);     // 0.5 MB

  cvt_f32_bf16<<<128, 256, 0, stream>>>(Wq, Wqb, 512 * 512 / 8);
  cvt_f32_bf16<<<256, 256, 0, stream>>>(Wkv, Wkvb, 1024 * 512 / 8);
  cvt_f32_bf16<<<128, 256, 0, stream>>>(Wproj, Wprojb, 512 * 512 / 8);

  // qh = (q @ Wq^T) * scale        M=4096, N=512   (A fp32 fused cvt)
  gemm8<0, true, false><<<32, 512, 0, stream>>>(q, Wqb, qhb, nullptr, 2, 512);
  // k  = kv @ Wk^T                 M=131072, N=512 (A fp32 fused cvt)
  gemm8<1, true, false><<<1024, 512, 0, stream>>>(kv, Wkvb, kbuf, nullptr, 2, 512);
  // vT = Wv @ kv^T                 M=512, N=131072 (B fp32 fused cvt)
  gemm8<1, false, true><<<1024, 512, 0, stream>>>(Wkvb + 512 * 512, kv, vTb, nullptr, 512, 131072);
  // flash attention partials
  attn_fwd<<<2048, 256, 0, stream>>>(qhb, kbuf, vTb, mask, opart, mlb);
  // combine -> xb bf16
  attn_combine<<<512, 256, 0, stream>>>(opart, mlb, xb);
  // out = x @ Wproj^T + bproj
  gemm8<2, false, false><<<32, 512, 0, stream>>>(xb, Wprojb, out, bproj, 2, 512);
}

// Round 6
// 448.917 us; speedup vs baseline: 1.0050x; 1.0050x over previous
//
#include <hip/hip_runtime.h>
#include <hip/hip_bf16.h>

typedef __attribute__((ext_vector_type(4))) float f32x4;
typedef __attribute__((ext_vector_type(8))) short bf16x8;

#define GAS __attribute__((address_space(1)))
#define LAS __attribute__((address_space(3)))

__device__ __forceinline__ unsigned int cvtpk(float lo, float hi) {
  unsigned int r;
  asm("v_cvt_pk_bf16_f32 %0, %1, %2" : "=v"(r) : "v"(lo), "v"(hi));
  return r;
}
__device__ __forceinline__ unsigned short f2bf(float f) { return (unsigned short)cvtpk(f, f); }
__device__ __forceinline__ f32x4 mfma16(bf16x8 a, bf16x8 b, f32x4 c) {
  return __builtin_amdgcn_mfma_f32_16x16x32_bf16(a, b, c, 0, 0, 0);
}
__device__ __forceinline__ void gl_lds16(const unsigned short* g, unsigned short* l) {
  __builtin_amdgcn_global_load_lds((const GAS unsigned short*)g, (LAS unsigned short*)l, 16, 0, 0);
}
__device__ __forceinline__ void memfence_sched() { asm volatile("" ::: "memory"); }

__global__ __launch_bounds__(256)
void cvt_f32_bf16(const float* __restrict__ in, unsigned short* __restrict__ out, int n8) {
  for (int i = blockIdx.x * blockDim.x + threadIdx.x; i < n8; i += gridDim.x * blockDim.x) {
    const float4 a = *reinterpret_cast<const float4*>(in + (size_t)i * 8);
    const float4 b = *reinterpret_cast<const float4*>(in + (size_t)i * 8 + 4);
    uint4 o;
    o.x = cvtpk(a.x, a.y); o.y = cvtpk(a.z, a.w);
    o.z = cvtpk(b.x, b.y); o.w = cvtpk(b.z, b.w);
    *reinterpret_cast<uint4*>(out + (size_t)i * 8) = o;
  }
}

// C[M,N] = A[M,512] @ B[N,512]^T. MIXED path (one operand fp32 F, one bf16 G):
// F reg-staged depth-2 (2 reg banks) + cvt_pk + swizzled ds_write, 2 LDS slots;
// G via global_load_lds depth-1 (2 LDS slots, L2-hot weights, pre-swizzled src).
// LDS = 64 KB -> 2 blocks/CU. Issue order per step: G(kt+1)[2], F(kt+2)[4];
// steady waits: mid vmcnt(6) -> F_WRITE(kt+1); end vmcnt(4). Tail 2 -> 0.
// Pure-bf16 path: both gl_lds depth-2, 3 slots each (96 KB; only tiny grids).
// 256x256 tile, 512 thr (8 waves 2x4), per-wave 128x64.
// MODE 0: bf16 *0.125 ; MODE 1: bf16 ; MODE 2: f32 + bias.
template<int MODE, bool AF32, bool BF32>
__global__ __launch_bounds__(512, 2)
void gemm8(const void* __restrict__ Agv, const void* __restrict__ Bgv,
           void* __restrict__ Cg, const float* __restrict__ bias, int ntn, size_t ldc)
{
  constexpr bool MIXED = AF32 || BF32;
  constexpr int NA = MIXED ? 2 : 3;
  constexpr int NB = MIXED ? 2 : 3;
  __shared__ unsigned short sm[(NA + NB) * 8192];
  unsigned short* const smB = sm + NA * 8192;

  const int t = threadIdx.x, lane = t & 63, w = t >> 6;
  const int lo = lane & 15, hi = lane >> 4;
  const int wm = w >> 2, wn = w & 3;
  const int nwg = gridDim.x, bid = blockIdx.x;
  const int id = (bid & 7) * (nwg >> 3) + (bid >> 3);   // XCD swizzle (nwg%8==0)
  const int row0 = (id / ntn) * 256, col0 = (id % ntn) * 256;
  const int w16 = w * 16;

  const unsigned short* Ab = (const unsigned short*)Agv;
  const unsigned short* Bb = (const unsigned short*)Bgv;
  const float* Ff = AF32 ? (const float*)Agv : (const float*)Bgv;
  const int frow0 = AF32 ? row0 : col0;

  // gl_lds path addressing (pre-swizzled source)
  const int cxor_g = (lane >> 3) & 3;
  const size_t a_src_g = (size_t)(row0 + w16 + (lane >> 2)) * 512 + (((lane & 3) ^ cxor_g) << 3);
  const size_t b_src_g = (size_t)(col0 + w16 + (lane >> 2)) * 512 + (((lane & 3) ^ cxor_g) << 3);

  // f32 reg-staged addressing
  const int rs_r = t >> 2;                 // row within 128-row half
  const int rs_c = (t & 3) * 8;            // col within 32
  const int wch = ((t & 3) ^ ((t >> 3) & 3)) << 3;   // swizzled ush offset in row

  float4 stF[2][4];                        // [bank = kt&1][piece]

  auto F_ISSUE = [&](int kt) {
    if constexpr (MIXED) {
      const int bk = kt & 1;
      const float* s0 = Ff + (size_t)(frow0 + rs_r) * 512 + kt * 32 + rs_c;
      const float* s1 = Ff + (size_t)(frow0 + 128 + rs_r) * 512 + kt * 32 + rs_c;
      stF[bk][0] = *(const float4*)s0; stF[bk][1] = *(const float4*)(s0 + 4);
      stF[bk][2] = *(const float4*)s1; stF[bk][3] = *(const float4*)(s1 + 4);
    }
  };
  auto F_WRITE = [&](int kt) {
    if constexpr (MIXED) {
      const int bk = kt & 1;
      unsigned short* fb = AF32 ? &sm[(kt % NA) * 8192] : &smB[(kt % NB) * 8192];
      uint4 o;
      o.x = cvtpk(stF[bk][0].x, stF[bk][0].y); o.y = cvtpk(stF[bk][0].z, stF[bk][0].w);
      o.z = cvtpk(stF[bk][1].x, stF[bk][1].y); o.w = cvtpk(stF[bk][1].z, stF[bk][1].w);
      *reinterpret_cast<uint4*>(&fb[rs_r * 32 + wch]) = o;
      o.x = cvtpk(stF[bk][2].x, stF[bk][2].y); o.y = cvtpk(stF[bk][2].z, stF[bk][2].w);
      o.z = cvtpk(stF[bk][3].x, stF[bk][3].y); o.w = cvtpk(stF[bk][3].z, stF[bk][3].w);
      *reinterpret_cast<uint4*>(&fb[(128 + rs_r) * 32 + wch]) = o;
    }
  };
  auto G_ISSUE = [&](int kt) {
    if constexpr (!AF32) {                 // A via gl_lds
      unsigned short* ab = &sm[(kt % NA) * 8192];
      gl_lds16(Ab + a_src_g + kt * 32, ab + w16 * 32);
      gl_lds16(Ab + a_src_g + (size_t)128 * 512 + kt * 32, ab + (128 + w16) * 32);
    }
    if constexpr (!BF32) {                 // B via gl_lds
      unsigned short* bb = &smB[(kt % NB) * 8192];
      gl_lds16(Bb + b_src_g + kt * 32, bb + w16 * 32);
      gl_lds16(Bb + b_src_g + (size_t)128 * 512 + kt * 32, bb + (128 + w16) * 32);
    }
  };

  f32x4 acc[8][4] = {};
  const int fxor = (hi ^ ((lo >> 1) & 3)) << 3;

  // ---- prologue ----
  if constexpr (MIXED) {
    F_ISSUE(0);                          // +4
    G_ISSUE(0);                          // +2
    F_ISSUE(1);                          // +4  -> 10 outstanding
    memfence_sched();
    asm volatile("s_waitcnt vmcnt(6)" ::: "memory");   // F(0) done
    F_WRITE(0);
    asm volatile("s_waitcnt vmcnt(4)" ::: "memory");   // G(0) done
  } else {
    G_ISSUE(0); G_ISSUE(1);
    memfence_sched();
    asm volatile("s_waitcnt vmcnt(4)" ::: "memory");    // stage 0 done
  }
  asm volatile("s_waitcnt lgkmcnt(0)" ::: "memory");
  __builtin_amdgcn_s_barrier();
  memfence_sched();

  // ---- main loop ----
  #pragma unroll
  for (int kt = 0; kt < 16; ++kt) {
    const unsigned short* ab = &sm[(kt % NA) * 8192];
    const unsigned short* bb = &smB[(kt % NB) * 8192];
    bf16x8 bfr[4], af[4];
    #pragma unroll
    for (int nj = 0; nj < 4; ++nj)
      bfr[nj] = *reinterpret_cast<const bf16x8*>(&bb[(wn * 64 + nj * 16 + lo) * 32 + fxor]);
    #pragma unroll
    for (int mi = 0; mi < 4; ++mi)
      af[mi] = *reinterpret_cast<const bf16x8*>(&ab[(wm * 128 + mi * 16 + lo) * 32 + fxor]);

    if constexpr (MIXED) {
      if (kt <= 14) G_ISSUE(kt + 1);
      if (kt <= 13) F_ISSUE(kt + 2);
    } else {
      if (kt <= 13) G_ISSUE(kt + 2);
    }
    memfence_sched();

    __builtin_amdgcn_s_setprio(1);
    #pragma unroll
    for (int mi = 0; mi < 4; ++mi)
      #pragma unroll
      for (int nj = 0; nj < 4; ++nj)
        acc[mi][nj] = mfma16(af[mi], bfr[nj], acc[mi][nj]);
    __builtin_amdgcn_s_setprio(0);

    #pragma unroll
    for (int mi = 0; mi < 4; ++mi)
      af[mi] = *reinterpret_cast<const bf16x8*>(&ab[(wm * 128 + (mi + 4) * 16 + lo) * 32 + fxor]);

    if constexpr (MIXED) {
      if (kt <= 13)      { asm volatile("s_waitcnt vmcnt(6)" ::: "memory"); }
      else if (kt == 14) { asm volatile("s_waitcnt vmcnt(2)" ::: "memory"); }
      if (kt <= 14) F_WRITE(kt + 1);
    }

    __builtin_amdgcn_s_setprio(1);
    #pragma unroll
    for (int mi = 0; mi < 4; ++mi)
      #pragma unroll
      for (int nj = 0; nj < 4; ++nj)
        acc[mi + 4][nj] = mfma16(af[mi], bfr[nj], acc[mi + 4][nj]);
    __builtin_amdgcn_s_setprio(0);

    if (kt < 15) {
      if constexpr (MIXED) {
        if (kt <= 13)      { asm volatile("s_waitcnt vmcnt(4)" ::: "memory"); }
        else               { asm volatile("s_waitcnt vmcnt(0)" ::: "memory"); }
      } else {
        if (kt <= 13)      { asm volatile("s_waitcnt vmcnt(4)" ::: "memory"); }
        else               { asm volatile("s_waitcnt vmcnt(0)" ::: "memory"); }
      }
      asm volatile("s_waitcnt lgkmcnt(0)" ::: "memory");
      __builtin_amdgcn_s_barrier();
      memfence_sched();
    }
  }

  #pragma unroll
  for (int mi = 0; mi < 8; ++mi) {
    #pragma unroll
    for (int r = 0; r < 4; ++r) {
      const size_t gm = (size_t)row0 + wm * 128 + mi * 16 + hi * 4 + r;
      #pragma unroll
      for (int nj = 0; nj < 4; ++nj) {
        const int gn = col0 + wn * 64 + nj * 16 + lo;
        const float v = acc[mi][nj][r];
        if constexpr (MODE == 0)
          ((unsigned short*)Cg)[gm * ldc + gn] = f2bf(v * 0.125f);
        else if constexpr (MODE == 1)
          ((unsigned short*)Cg)[gm * ldc + gn] = f2bf(v);
        else
          ((float*)Cg)[gm * ldc + gn] = v + bias[gn];
      }
    }
  }
}

// Flash attention, KV split 4-way: grid = 2048 (b,h,qhalf,chunk), 256 thr
// (4 waves x 16 q-rows). Writes partials (o fp32, m, l) for combine pass.
// k [131072, 512] bf16 (col h*64+d); vT [512, 131072] bf16.
__global__ __launch_bounds__(256)
void attn_fwd(const unsigned short* __restrict__ qh,
              const unsigned short* __restrict__ kbuf,
              const unsigned short* __restrict__ vT,
              const float* __restrict__ mask,
              float* __restrict__ opart, float* __restrict__ ml)
{
  __shared__ unsigned short Ks[64 * 64];
  __shared__ unsigned short Vs[64 * 64];
  __shared__ unsigned short Ps[4][16 * 64];
  const int bid = blockIdx.x;
  const int xcd = bid & 7, g = bid >> 3;
  const int b = (g >> 6) * 8 + xcd;           // blocks sharing b land on one XCD
  const int sub = g & 63;
  const int h = sub >> 3, qhalf = (sub >> 2) & 1, c = sub & 3;
  const int n0 = c * 1024;
  const int bh2 = (b * 8 + h) * 2 + qhalf;
  const int t = threadIdx.x, lane = t & 63, w = t >> 6;
  const int hi = lane >> 4, lo = lane & 15;
  const int q0 = qhalf * 64 + w * 16;

  bf16x8 aq[2];
  #pragma unroll
  for (int kk = 0; kk < 2; ++kk)
    aq[kk] = *reinterpret_cast<const bf16x8*>(
        qh + (size_t)(b * 128 + q0 + lo) * 512 + h * 64 + kk * 32 + hi * 8);

  float mrow[4], lrow[4];
  #pragma unroll
  for (int i = 0; i < 4; ++i) { mrow[i] = -1e30f; lrow[i] = 0.f; }
  f32x4 o[4] = {};

  const unsigned short* kp = kbuf + ((size_t)b * 4096 + n0) * 512 + h * 64;
  const unsigned short* vp = vT + (size_t)(h * 64) * 131072 + (size_t)b * 4096 + n0;
  const float* mp = mask + ((size_t)(b * 128 + q0)) * 4096 + n0;

  for (int nt = 0; nt < 16; ++nt) {
    {
      const int r = t >> 3, cc = t & 7;
      *reinterpret_cast<uint4*>(&Ks[r * 64 + ((cc ^ (r & 7)) << 3)]) =
          *reinterpret_cast<const uint4*>(kp + (size_t)(nt * 64 + r) * 512 + (cc << 3));
      *reinterpret_cast<uint4*>(&Ks[(r + 32) * 64 + ((cc ^ (r & 7)) << 3)]) =
          *reinterpret_cast<const uint4*>(kp + (size_t)(nt * 64 + r + 32) * 512 + (cc << 3));
      *reinterpret_cast<uint4*>(&Vs[r * 64 + ((cc ^ (r & 7)) << 3)]) =
          *reinterpret_cast<const uint4*>(vp + (size_t)r * 131072 + nt * 64 + (cc << 3));
      *reinterpret_cast<uint4*>(&Vs[(r + 32) * 64 + ((cc ^ (r & 7)) << 3)]) =
          *reinterpret_cast<const uint4*>(vp + (size_t)(r + 32) * 131072 + nt * 64 + (cc << 3));
    }
    __syncthreads();

    f32x4 s[4] = {};
    __builtin_amdgcn_s_setprio(1);
    #pragma unroll
    for (int ni = 0; ni < 4; ++ni) {
      #pragma unroll
      for (int kk = 0; kk < 2; ++kk) {
        const bf16x8 kf = *reinterpret_cast<const bf16x8*>(
            &Ks[(ni * 16 + lo) * 64 + ((kk * 32 + hi * 8) ^ ((lo & 7) << 3))]);
        s[ni] = mfma16(aq[kk], kf, s[ni]);
      }
    }
    __builtin_amdgcn_s_setprio(0);
    #pragma unroll
    for (int ni = 0; ni < 4; ++ni)
      #pragma unroll
      for (int r = 0; r < 4; ++r)
        s[ni][r] += mp[(size_t)(hi * 4 + r) * 4096 + nt * 64 + ni * 16 + lo];

    #pragma unroll
    for (int r = 0; r < 4; ++r) {
      float mx = fmaxf(fmaxf(s[0][r], s[1][r]), fmaxf(s[2][r], s[3][r]));
      #pragma unroll
      for (int off = 1; off < 16; off <<= 1)
        mx = fmaxf(mx, __shfl_xor(mx, off, 64));
      const float mnew = fmaxf(mrow[r], mx);
      const float corr = __expf(mrow[r] - mnew);
      mrow[r] = mnew;
      float ls = 0.f;
      #pragma unroll
      for (int ni = 0; ni < 4; ++ni) {
        const float p = __expf(s[ni][r] - mnew);
        s[ni][r] = p; ls += p;
      }
      #pragma unroll
      for (int off = 1; off < 16; off <<= 1)
        ls += __shfl_xor(ls, off, 64);
      lrow[r] = lrow[r] * corr + ls;
      #pragma unroll
      for (int di = 0; di < 4; ++di)
        o[di][r] *= corr;
    }

    #pragma unroll
    for (int ni = 0; ni < 4; ++ni)
      #pragma unroll
      for (int r = 0; r < 4; ++r) {
        const int rp = hi * 4 + r;
        Ps[w][rp * 64 + ((ni * 16 + lo) ^ ((rp & 7) << 3))] = f2bf(s[ni][r]);
      }

    __builtin_amdgcn_s_setprio(1);
    #pragma unroll
    for (int kk = 0; kk < 2; ++kk) {
      const bf16x8 pa = *reinterpret_cast<const bf16x8*>(
          &Ps[w][lo * 64 + ((kk * 32 + hi * 8) ^ ((lo & 7) << 3))]);
      #pragma unroll
      for (int di = 0; di < 4; ++di) {
        const bf16x8 vf = *reinterpret_cast<const bf16x8*>(
            &Vs[(di * 16 + lo) * 64 + ((kk * 32 + hi * 8) ^ ((lo & 7) << 3))]);
        o[di] = mfma16(pa, vf, o[di]);
      }
    }
    __builtin_amdgcn_s_setprio(0);
    __syncthreads();
  }

  // store partials (no division)
  const size_t pbase = ((size_t)bh2 * 4 + c) * 64;
  #pragma unroll
  for (int di = 0; di < 4; ++di)
    #pragma unroll
    for (int r = 0; r < 4; ++r)
      opart[(pbase + (w * 16 + hi * 4 + r)) * 64 + di * 16 + lo] = o[di][r];
  if (lo == 0) {
    #pragma unroll
    for (int r = 0; r < 4; ++r) {
      const int qq = w * 16 + hi * 4 + r;
      ml[(((size_t)bh2 * 4 + c) * 2 + 0) * 64 + qq] = mrow[r];
      ml[(((size_t)bh2 * 4 + c) * 2 + 1) * 64 + qq] = lrow[r];
    }
  }
}

// Combine 4 chunk-partials -> xb bf16. grid = 512 (bh2), 256 thr.
__global__ __launch_bounds__(256)
void attn_combine(const float* __restrict__ opart, const float* __restrict__ ml,
                  unsigned short* __restrict__ xb)
{
  const int bh2 = blockIdx.x;
  const int b = bh2 >> 4, h = (bh2 >> 1) & 7, qhalf = bh2 & 1;
  const int t = threadIdx.x;
  const int q = t >> 2, dg = t & 3;

  float m[4], l[4];
  #pragma unroll
  for (int c = 0; c < 4; ++c) {
    m[c] = ml[(((size_t)bh2 * 4 + c) * 2 + 0) * 64 + q];
    l[c] = ml[(((size_t)bh2 * 4 + c) * 2 + 1) * 64 + q];
  }
  const float M = fmaxf(fmaxf(m[0], m[1]), fmaxf(m[2], m[3]));
  float sc[4], L = 0.f;
  #pragma unroll
  for (int c = 0; c < 4; ++c) { sc[c] = __expf(m[c] - M); L += sc[c] * l[c]; }
  const float inv = 1.f / L;

  float4 acc[4] = {};
  #pragma unroll
  for (int c = 0; c < 4; ++c) {
    const float* base = opart + (((size_t)bh2 * 4 + c) * 64 + q) * 64 + dg * 16;
    #pragma unroll
    for (int j = 0; j < 4; ++j) {
      const float4 v = *reinterpret_cast<const float4*>(base + j * 4);
      acc[j].x = fmaf(sc[c], v.x, acc[j].x);
      acc[j].y = fmaf(sc[c], v.y, acc[j].y);
      acc[j].z = fmaf(sc[c], v.z, acc[j].z);
      acc[j].w = fmaf(sc[c], v.w, acc[j].w);
    }
  }
  unsigned short* dst = xb + ((size_t)b * 128 + qhalf * 64 + q) * 512 + h * 64 + dg * 16;
  uint4 o1, o2;
  o1.x = cvtpk(acc[0].x * inv, acc[0].y * inv); o1.y = cvtpk(acc[0].z * inv, acc[0].w * inv);
  o1.z = cvtpk(acc[1].x * inv, acc[1].y * inv); o1.w = cvtpk(acc[1].z * inv, acc[1].w * inv);
  o2.x = cvtpk(acc[2].x * inv, acc[2].y * inv); o2.y = cvtpk(acc[2].z * inv, acc[2].w * inv);
  o2.z = cvtpk(acc[3].x * inv, acc[3].y * inv); o2.w = cvtpk(acc[3].z * inv, acc[3].w * inv);
  *reinterpret_cast<uint4*>(dst) = o1;
  *reinterpret_cast<uint4*>(dst + 8) = o2;
}

extern "C" void kernel_launch(void* const* d_in, const int* in_sizes, int n_in,
                              void* d_out, int out_size, void* d_ws, size_t ws_size,
                              hipStream_t stream) {
  const float* q     = (const float*)d_in[0];
  const float* kv    = (const float*)d_in[1];
  const float* mask  = (const float*)d_in[2];
  const float* Wq    = (const float*)d_in[3];
  const float* Wkv   = (const float*)d_in[4];
  const float* Wproj = (const float*)d_in[5];
  const float* bproj = (const float*)d_in[6];
  float* out = (float*)d_out;

  char* ws = (char*)d_ws;
  unsigned short* kbuf   = (unsigned short*)ws;                      // 134.2 MB [131072,512]
  unsigned short* vTb    = (unsigned short*)(ws + 134217728ULL);     // 134.2 MB [512,131072]
  float*          opart  = (float*)(ws + 268435456ULL);              // 33.6 MB [512][4][64][64]
  float*          mlb    = (float*)(ws + 301989888ULL);              // 1.0 MB  [512][4][2][64]
  unsigned short* qhb    = (unsigned short*)(ws + 303038464ULL);     // 4.2 MB
  unsigned short* xb     = (unsigned short*)(ws + 307232768ULL);     // 4.2 MB
  unsigned short* Wqb    = (unsigned short*)(ws + 311427072ULL);     // 0.5 MB
  unsigned short* Wkvb   = (unsigned short*)(ws + 311951360ULL);     // 1.0 MB
  unsigned short* Wprojb = (unsigned short*)(ws + 312999936ULL);     // 0.5 MB

  cvt_f32_bf16<<<128, 256, 0, stream>>>(Wq, Wqb, 512 * 512 / 8);
  cvt_f32_bf16<<<256, 256, 0, stream>>>(Wkv, Wkvb, 1024 * 512 / 8);
  cvt_f32_bf16<<<128, 256, 0, stream>>>(Wproj, Wprojb, 512 * 512 / 8);

  // qh = (q @ Wq^T) * scale        M=4096, N=512   (A fp32 fused cvt)
  gemm8<0, true, false><<<32, 512, 0, stream>>>(q, Wqb, qhb, nullptr, 2, 512);
  // k  = kv @ Wk^T                 M=131072, N=512 (A fp32 fused cvt)
  gemm8<1, true, false><<<1024, 512, 0, stream>>>(kv, Wkvb, kbuf, nullptr, 2, 512);
  // vT = Wv @ kv^T                 M=512, N=131072 (B fp32 fused cvt)
  gemm8<1, false, true><<<1024, 512, 0, stream>>>(Wkvb + 512 * 512, kv, vTb, nullptr, 512, 131072);
  // flash attention partials
  attn_fwd<<<2048, 256, 0, stream>>>(qhb, kbuf, vTb, mask, opart, mlb);
  // combine -> xb bf16
  attn_combine<<<512, 256, 0, stream>>>(opart, mlb, xb);
  // out = x @ Wproj^T + bproj
  gemm8<2, false, false><<<32, 512, 0, stream>>>(xb, Wprojb, out, bproj, 2, 512);
}

// Round 7
// 439.710 us; speedup vs baseline: 1.0260x; 1.0209x over previous
//
#include <hip/hip_runtime.h>
#include <hip/hip_bf16.h>

typedef __attribute__((ext_vector_type(4))) float f32x4;
typedef __attribute__((ext_vector_type(8))) short bf16x8;

#define GAS __attribute__((address_space(1)))
#define LAS __attribute__((address_space(3)))

__device__ __forceinline__ unsigned int cvtpk(float lo, float hi) {
  unsigned int r;
  asm("v_cvt_pk_bf16_f32 %0, %1, %2" : "=v"(r) : "v"(lo), "v"(hi));
  return r;
}
__device__ __forceinline__ unsigned short f2bf(float f) { return (unsigned short)cvtpk(f, f); }
__device__ __forceinline__ f32x4 mfma16(bf16x8 a, bf16x8 b, f32x4 c) {
  return __builtin_amdgcn_mfma_f32_16x16x32_bf16(a, b, c, 0, 0, 0);
}
__device__ __forceinline__ void gl_lds16(const unsigned short* g, unsigned short* l) {
  __builtin_amdgcn_global_load_lds((const GAS unsigned short*)g, (LAS unsigned short*)l, 16, 0, 0);
}
__device__ __forceinline__ void memfence_sched() { asm volatile("" ::: "memory"); }

__global__ __launch_bounds__(256)
void cvt_f32_bf16(const float* __restrict__ in, unsigned short* __restrict__ out, int n8) {
  for (int i = blockIdx.x * blockDim.x + threadIdx.x; i < n8; i += gridDim.x * blockDim.x) {
    const float4 a = *reinterpret_cast<const float4*>(in + (size_t)i * 8);
    const float4 b = *reinterpret_cast<const float4*>(in + (size_t)i * 8 + 4);
    uint4 o;
    o.x = cvtpk(a.x, a.y); o.y = cvtpk(a.z, a.w);
    o.z = cvtpk(b.x, b.y); o.w = cvtpk(b.z, b.w);
    *reinterpret_cast<uint4*>(out + (size_t)i * 8) = o;
  }
}

// Pure-bf16 phase-interleaved GEMM: C[M,N] = A[M,512] @ B[N,512]^T.
// 256x256 tile, BK=32, 16 K-tiles, 512 thr (8 waves 2x4), per-wave 128x64.
// NBUF=3 LDS buffers per operand (96 KB total), both operands staged via
// global_load_lds 2 K-tiles ahead -> steady s_waitcnt vmcnt(4), never drains
// until the tail (T3+T4). Per K-tile: 2 sub-phases, each {ds_read frags ||
// 2 gl_lds stage -> barrier -> 16 MFMA in setprio (T5) -> barrier}.
// st_16x32 swizzle (T2): LDS[r][c] holds global col c ^ ((r>>3&1)<<4);
// applied via pre-swizzled gl_lds SOURCE + swizzled ds_read (rule 21).
// MODE 0: bf16 out *0.125 ; MODE 1: bf16 out ; MODE 2: f32 out + bias.
template<int MODE>
__global__ __launch_bounds__(512, 2)
void gemm8p(const unsigned short* __restrict__ Ag, const unsigned short* __restrict__ Bg,
            void* __restrict__ Cg, const float* __restrict__ bias, int ntn, size_t ldc)
{
  __shared__ unsigned short sm[49152];   // A: (buf*2+half)*4096 ; B: +24576
  const int t = threadIdx.x, lane = t & 63, w = t >> 6;
  const int lo = lane & 15, hi = lane >> 4;
  const int wm = w >> 2, wn = w & 3;
  const int nwg = gridDim.x, bid = blockIdx.x;
  const int id = (bid & 7) * (nwg >> 3) + (bid >> 3);   // XCD swizzle (nwg%8==0)
  const int row0 = (id / ntn) * 256, col0 = (id % ntn) * 256;

  // gl_lds source (pre-swizzled): thread t covers half-tile row t>>2,
  // cols ((t&3)*8) ^ ((t>>5 &1)<<4) .. +7 of the 32-col K-tile.
  const int gcol = ((t & 3) * 8) ^ (((t >> 5) & 1) << 4);
  const int grow = t >> 2;
  const unsigned short* aS = Ag + (size_t)(row0 + grow) * 512 + gcol;
  const unsigned short* bS = Bg + (size_t)(col0 + grow) * 512 + gcol;
  const int wds = w * 512;                // per-wave linear LDS segment (ush)

  auto STAGE_A = [&](int kt) {
    const int bf = kt % 3;
    gl_lds16(aS + kt * 32,         &sm[(bf * 2 + 0) * 4096 + wds]);
    gl_lds16(aS + kt * 32 + 65536, &sm[(bf * 2 + 1) * 4096 + wds]);  // +128 rows
  };
  auto STAGE_B = [&](int kt) {
    const int bf = kt % 3;
    gl_lds16(bS + kt * 32,         &sm[24576 + (bf * 2 + 0) * 4096 + wds]);
    gl_lds16(bS + kt * 32 + 65536, &sm[24576 + (bf * 2 + 1) * 4096 + wds]);
  };

  f32x4 acc[8][4] = {};
  const int fc = (hi * 8) ^ (((lo >> 3) & 1) << 4);   // swizzled frag col (ush)
  const int rbB = (wn & 1) * 64;                      // B row base within half

  // prologue: stage K-tiles 0,1 (8 loads)
  STAGE_A(0); STAGE_B(0); STAGE_A(1); STAGE_B(1);
  memfence_sched();
  asm volatile("s_waitcnt vmcnt(4)" ::: "memory");    // kt0 landed
  __builtin_amdgcn_s_barrier();
  memfence_sched();

  #pragma unroll
  for (int kt = 0; kt < 16; ++kt) {
    const int bf = kt % 3;
    const unsigned short* aB = &sm[(bf * 2 + wm) * 4096];
    const unsigned short* bB = &sm[24576 + (bf * 2 + (wn >> 1)) * 4096];

    // ---- sub-phase 0: bfr + af(0-3) reads, stage A(kt+2), 16 MFMA ----
    bf16x8 bfr[4], af[4];
    #pragma unroll
    for (int nj = 0; nj < 4; ++nj)
      bfr[nj] = *reinterpret_cast<const bf16x8*>(&bB[(rbB + nj * 16 + lo) * 32 + fc]);
    #pragma unroll
    for (int mi = 0; mi < 4; ++mi)
      af[mi] = *reinterpret_cast<const bf16x8*>(&aB[(mi * 16 + lo) * 32 + fc]);
    if (kt <= 13) STAGE_A(kt + 2);
    memfence_sched();
    __builtin_amdgcn_s_barrier();
    memfence_sched();
    __builtin_amdgcn_s_setprio(1);
    #pragma unroll
    for (int mi = 0; mi < 4; ++mi)
      #pragma unroll
      for (int nj = 0; nj < 4; ++nj)
        acc[mi][nj] = mfma16(af[mi], bfr[nj], acc[mi][nj]);
    __builtin_amdgcn_s_setprio(0);
    __builtin_amdgcn_s_barrier();
    memfence_sched();

    // ---- sub-phase 1: af(4-7) reads, stage B(kt+2), 16 MFMA ----
    #pragma unroll
    for (int mi = 0; mi < 4; ++mi)
      af[mi] = *reinterpret_cast<const bf16x8*>(&aB[((mi + 4) * 16 + lo) * 32 + fc]);
    if (kt <= 13) STAGE_B(kt + 2);
    memfence_sched();
    __builtin_amdgcn_s_barrier();
    memfence_sched();
    __builtin_amdgcn_s_setprio(1);
    #pragma unroll
    for (int mi = 0; mi < 4; ++mi)
      #pragma unroll
      for (int nj = 0; nj < 4; ++nj)
        acc[mi + 4][nj] = mfma16(af[mi], bfr[nj], acc[mi + 4][nj]);
    __builtin_amdgcn_s_setprio(0);
    if (kt <= 13)      { asm volatile("s_waitcnt vmcnt(4)" ::: "memory"); }  // kt+1 ready
    else if (kt == 14) { asm volatile("s_waitcnt vmcnt(0)" ::: "memory"); }  // tail drain
    if (kt < 15) { __builtin_amdgcn_s_barrier(); memfence_sched(); }
  }

  #pragma unroll
  for (int mi = 0; mi < 8; ++mi) {
    #pragma unroll
    for (int r = 0; r < 4; ++r) {
      const size_t gm = (size_t)row0 + wm * 128 + mi * 16 + hi * 4 + r;
      #pragma unroll
      for (int nj = 0; nj < 4; ++nj) {
        const int gn = col0 + wn * 64 + nj * 16 + lo;
        const float v = acc[mi][nj][r];
        if constexpr (MODE == 0)
          ((unsigned short*)Cg)[gm * ldc + gn] = f2bf(v * 0.125f);
        else if constexpr (MODE == 1)
          ((unsigned short*)Cg)[gm * ldc + gn] = f2bf(v);
        else
          ((float*)Cg)[gm * ldc + gn] = v + bias[gn];
      }
    }
  }
}

// Flash attention, KV split 4-way: grid = 2048 (b,h,qhalf,chunk), 256 thr
// (4 waves x 16 q-rows). Writes partials (o fp32, m, l) for combine pass.
// k [131072, 512] bf16 (col h*64+d); vT [512, 131072] bf16.
__global__ __launch_bounds__(256)
void attn_fwd(const unsigned short* __restrict__ qh,
              const unsigned short* __restrict__ kbuf,
              const unsigned short* __restrict__ vT,
              const float* __restrict__ mask,
              float* __restrict__ opart, float* __restrict__ ml)
{
  __shared__ unsigned short Ks[64 * 64];
  __shared__ unsigned short Vs[64 * 64];
  __shared__ unsigned short Ps[4][16 * 64];
  const int bid = blockIdx.x;
  const int xcd = bid & 7, g = bid >> 3;
  const int b = (g >> 6) * 8 + xcd;           // blocks sharing b land on one XCD
  const int sub = g & 63;
  const int h = sub >> 3, qhalf = (sub >> 2) & 1, c = sub & 3;
  const int n0 = c * 1024;
  const int bh2 = (b * 8 + h) * 2 + qhalf;
  const int t = threadIdx.x, lane = t & 63, w = t >> 6;
  const int hi = lane >> 4, lo = lane & 15;
  const int q0 = qhalf * 64 + w * 16;

  bf16x8 aq[2];
  #pragma unroll
  for (int kk = 0; kk < 2; ++kk)
    aq[kk] = *reinterpret_cast<const bf16x8*>(
        qh + (size_t)(b * 128 + q0 + lo) * 512 + h * 64 + kk * 32 + hi * 8);

  float mrow[4], lrow[4];
  #pragma unroll
  for (int i = 0; i < 4; ++i) { mrow[i] = -1e30f; lrow[i] = 0.f; }
  f32x4 o[4] = {};

  const unsigned short* kp = kbuf + ((size_t)b * 4096 + n0) * 512 + h * 64;
  const unsigned short* vp = vT + (size_t)(h * 64) * 131072 + (size_t)b * 4096 + n0;
  const float* mp = mask + ((size_t)(b * 128 + q0)) * 4096 + n0;

  for (int nt = 0; nt < 16; ++nt) {
    {
      const int r = t >> 3, cc = t & 7;
      *reinterpret_cast<uint4*>(&Ks[r * 64 + ((cc ^ (r & 7)) << 3)]) =
          *reinterpret_cast<const uint4*>(kp + (size_t)(nt * 64 + r) * 512 + (cc << 3));
      *reinterpret_cast<uint4*>(&Ks[(r + 32) * 64 + ((cc ^ (r & 7)) << 3)]) =
          *reinterpret_cast<const uint4*>(kp + (size_t)(nt * 64 + r + 32) * 512 + (cc << 3));
      *reinterpret_cast<uint4*>(&Vs[r * 64 + ((cc ^ (r & 7)) << 3)]) =
          *reinterpret_cast<const uint4*>(vp + (size_t)r * 131072 + nt * 64 + (cc << 3));
      *reinterpret_cast<uint4*>(&Vs[(r + 32) * 64 + ((cc ^ (r & 7)) << 3)]) =
          *reinterpret_cast<const uint4*>(vp + (size_t)(r + 32) * 131072 + nt * 64 + (cc << 3));
    }
    __syncthreads();

    f32x4 s[4] = {};
    __builtin_amdgcn_s_setprio(1);
    #pragma unroll
    for (int ni = 0; ni < 4; ++ni) {
      #pragma unroll
      for (int kk = 0; kk < 2; ++kk) {
        const bf16x8 kf = *reinterpret_cast<const bf16x8*>(
            &Ks[(ni * 16 + lo) * 64 + ((kk * 32 + hi * 8) ^ ((lo & 7) << 3))]);
        s[ni] = mfma16(aq[kk], kf, s[ni]);
      }
    }
    __builtin_amdgcn_s_setprio(0);
    #pragma unroll
    for (int ni = 0; ni < 4; ++ni)
      #pragma unroll
      for (int r = 0; r < 4; ++r)
        s[ni][r] += mp[(size_t)(hi * 4 + r) * 4096 + nt * 64 + ni * 16 + lo];

    #pragma unroll
    for (int r = 0; r < 4; ++r) {
      float mx = fmaxf(fmaxf(s[0][r], s[1][r]), fmaxf(s[2][r], s[3][r]));
      #pragma unroll
      for (int off = 1; off < 16; off <<= 1)
        mx = fmaxf(mx, __shfl_xor(mx, off, 64));
      const float mnew = fmaxf(mrow[r], mx);
      const float corr = __expf(mrow[r] - mnew);
      mrow[r] = mnew;
      float ls = 0.f;
      #pragma unroll
      for (int ni = 0; ni < 4; ++ni) {
        const float p = __expf(s[ni][r] - mnew);
        s[ni][r] = p; ls += p;
      }
      #pragma unroll
      for (int off = 1; off < 16; off <<= 1)
        ls += __shfl_xor(ls, off, 64);
      lrow[r] = lrow[r] * corr + ls;
      #pragma unroll
      for (int di = 0; di < 4; ++di)
        o[di][r] *= corr;
    }

    #pragma unroll
    for (int ni = 0; ni < 4; ++ni)
      #pragma unroll
      for (int r = 0; r < 4; ++r) {
        const int rp = hi * 4 + r;
        Ps[w][rp * 64 + ((ni * 16 + lo) ^ ((rp & 7) << 3))] = f2bf(s[ni][r]);
      }

    __builtin_amdgcn_s_setprio(1);
    #pragma unroll
    for (int kk = 0; kk < 2; ++kk) {
      const bf16x8 pa = *reinterpret_cast<const bf16x8*>(
          &Ps[w][lo * 64 + ((kk * 32 + hi * 8) ^ ((lo & 7) << 3))]);
      #pragma unroll
      for (int di = 0; di < 4; ++di) {
        const bf16x8 vf = *reinterpret_cast<const bf16x8*>(
            &Vs[(di * 16 + lo) * 64 + ((kk * 32 + hi * 8) ^ ((lo & 7) << 3))]);
        o[di] = mfma16(pa, vf, o[di]);
      }
    }
    __builtin_amdgcn_s_setprio(0);
    __syncthreads();
  }

  // store partials (no division)
  const size_t pbase = ((size_t)bh2 * 4 + c) * 64;
  #pragma unroll
  for (int di = 0; di < 4; ++di)
    #pragma unroll
    for (int r = 0; r < 4; ++r)
      opart[(pbase + (w * 16 + hi * 4 + r)) * 64 + di * 16 + lo] = o[di][r];
  if (lo == 0) {
    #pragma unroll
    for (int r = 0; r < 4; ++r) {
      const int qq = w * 16 + hi * 4 + r;
      ml[(((size_t)bh2 * 4 + c) * 2 + 0) * 64 + qq] = mrow[r];
      ml[(((size_t)bh2 * 4 + c) * 2 + 1) * 64 + qq] = lrow[r];
    }
  }
}

// Combine 4 chunk-partials -> xb bf16. grid = 512 (bh2), 256 thr.
__global__ __launch_bounds__(256)
void attn_combine(const float* __restrict__ opart, const float* __restrict__ ml,
                  unsigned short* __restrict__ xb)
{
  const int bh2 = blockIdx.x;
  const int b = bh2 >> 4, h = (bh2 >> 1) & 7, qhalf = bh2 & 1;
  const int t = threadIdx.x;
  const int q = t >> 2, dg = t & 3;

  float m[4], l[4];
  #pragma unroll
  for (int c = 0; c < 4; ++c) {
    m[c] = ml[(((size_t)bh2 * 4 + c) * 2 + 0) * 64 + q];
    l[c] = ml[(((size_t)bh2 * 4 + c) * 2 + 1) * 64 + q];
  }
  const float M = fmaxf(fmaxf(m[0], m[1]), fmaxf(m[2], m[3]));
  float sc[4], L = 0.f;
  #pragma unroll
  for (int c = 0; c < 4; ++c) { sc[c] = __expf(m[c] - M); L += sc[c] * l[c]; }
  const float inv = 1.f / L;

  float4 acc[4] = {};
  #pragma unroll
  for (int c = 0; c < 4; ++c) {
    const float* base = opart + (((size_t)bh2 * 4 + c) * 64 + q) * 64 + dg * 16;
    #pragma unroll
    for (int j = 0; j < 4; ++j) {
      const float4 v = *reinterpret_cast<const float4*>(base + j * 4);
      acc[j].x = fmaf(sc[c], v.x, acc[j].x);
      acc[j].y = fmaf(sc[c], v.y, acc[j].y);
      acc[j].z = fmaf(sc[c], v.z, acc[j].z);
      acc[j].w = fmaf(sc[c], v.w, acc[j].w);
    }
  }
  unsigned short* dst = xb + ((size_t)b * 128 + qhalf * 64 + q) * 512 + h * 64 + dg * 16;
  uint4 o1, o2;
  o1.x = cvtpk(acc[0].x * inv, acc[0].y * inv); o1.y = cvtpk(acc[0].z * inv, acc[0].w * inv);
  o1.z = cvtpk(acc[1].x * inv, acc[1].y * inv); o1.w = cvtpk(acc[1].z * inv, acc[1].w * inv);
  o2.x = cvtpk(acc[2].x * inv, acc[2].y * inv); o2.y = cvtpk(acc[2].z * inv, acc[2].w * inv);
  o2.z = cvtpk(acc[3].x * inv, acc[3].y * inv); o2.w = cvtpk(acc[3].z * inv, acc[3].w * inv);
  *reinterpret_cast<uint4*>(dst) = o1;
  *reinterpret_cast<uint4*>(dst + 8) = o2;
}

extern "C" void kernel_launch(void* const* d_in, const int* in_sizes, int n_in,
                              void* d_out, int out_size, void* d_ws, size_t ws_size,
                              hipStream_t stream) {
  const float* q     = (const float*)d_in[0];
  const float* kv    = (const float*)d_in[1];
  const float* mask  = (const float*)d_in[2];
  const float* Wq    = (const float*)d_in[3];
  const float* Wkv   = (const float*)d_in[4];
  const float* Wproj = (const float*)d_in[5];
  const float* bproj = (const float*)d_in[6];
  float* out = (float*)d_out;

  char* ws = (char*)d_ws;
  unsigned short* kbuf   = (unsigned short*)ws;                      // 134.2 MB [131072,512]
  unsigned short* vTb    = (unsigned short*)(ws + 134217728ULL);     // 134.2 MB [512,131072]
  unsigned short* kvbfc  = (unsigned short*)(ws + 268435456ULL);     // 67.1 MB rotating bf16 chunk
  unsigned short* qbf    = kvbfc;                                    // 4.2 MB (alias, pre-chunk)
  float*          opart  = (float*)(ws + 268435456ULL);              // 33.6 MB (alias, post-chunk)
  float*          mlb    = (float*)(ws + 301989888ULL);              // 1.0 MB  (alias)
  unsigned short* xb     = (unsigned short*)(ws + 303038464ULL);     // 4.2 MB  (alias)
  unsigned short* qhb    = (unsigned short*)(ws + 335544320ULL);     // 4.2 MB
  unsigned short* Wqb    = (unsigned short*)(ws + 339738624ULL);     // 0.5 MB
  unsigned short* Wkvb   = (unsigned short*)(ws + 340262912ULL);     // 1.0 MB
  unsigned short* Wprojb = (unsigned short*)(ws + 341311488ULL);     // 0.5 MB

  cvt_f32_bf16<<<128, 256, 0, stream>>>(Wq, Wqb, 512 * 512 / 8);
  cvt_f32_bf16<<<256, 256, 0, stream>>>(Wkv, Wkvb, 1024 * 512 / 8);
  cvt_f32_bf16<<<128, 256, 0, stream>>>(Wproj, Wprojb, 512 * 512 / 8);

  // qh = (q @ Wq^T) * scale   (qbf aliases kvbfc; consumed before kv chunks)
  cvt_f32_bf16<<<256, 256, 0, stream>>>(q, qbf, 4096 * 512 / 8);
  gemm8p<0><<<32, 512, 0, stream>>>(qbf, Wqb, qhb, nullptr, 2, 512);

  for (int c = 0; c < 2; ++c) {
    cvt_f32_bf16<<<2048, 256, 0, stream>>>(kv + (size_t)c * 65536 * 512, kvbfc,
                                           65536 * 512 / 8);
    // k chunk: kvbf [65536,512] @ Wk^T -> kbuf rows
    gemm8p<1><<<512, 512, 0, stream>>>(kvbfc, Wkvb,
                                       kbuf + (size_t)c * 65536 * 512, nullptr, 2, 512);
    // vT chunk: Wv @ kvbf^T -> vT[512, 65536-slice]
    gemm8p<1><<<512, 512, 0, stream>>>(Wkvb + 512 * 512, kvbfc,
                                       vTb + (size_t)c * 65536, nullptr, 256, 131072);
  }

  // flash attention partials (kbuf/vT layouts unchanged)
  attn_fwd<<<2048, 256, 0, stream>>>(qhb, kbuf, vTb, mask, opart, mlb);
  // combine -> xb bf16
  attn_combine<<<512, 256, 0, stream>>>(opart, mlb, xb);
  // out = x @ Wproj^T + bproj
  gemm8p<2><<<32, 512, 0, stream>>>(xb, Wprojb, out, bproj, 2, 512);
}